// Round 6
// baseline (458.473 us; speedup 1.0000x reference)
//
#include <hip/hip_runtime.h>
#include <math.h>

#define Bn 4
#define Cn 128
#define Hn 256
#define Wn 256
#define WFn 129
#define NBn 8
#define BLn 16
#define LAMv 0.01f
// LDS row stride (floats). 272 = 16 mod 32 banks: the 4 c-groups of a wave
// land on complementary bank halves -> exact 2-way aliasing (free) for the
// four-step transpose, h-order stores, and MLP reads. Also 16B-aligned.
#define LSTR 272

#define C1c 0.9238795325112867f  // cos(pi/8)
#define S1c 0.3826834323650898f  // sin(pi/8)
#define RTc 0.7071067811865476f  // sqrt(2)/2

__device__ constexpr int rev4(int j) {
  return ((j & 1) << 3) | ((j & 2) << 1) | ((j & 4) >> 1) | ((j & 8) >> 3);
}

// elementwise float2 fma: SLP-vectorizes to v_pk_fma_f32 on gfx950
__device__ __forceinline__ float2 pkfma(float2 a, float2 b, float2 c) {
  return make_float2(fmaf(a.x, b.x, c.x), fmaf(a.y, b.y, c.y));
}

// Twiddle table: twt[s*16+k2] = e^{-i*pi*s*k2/128} = (cos, -sin).
// Built once per block by 256 threads (1 sincospif each); caller must have a
// __syncthreads() between this and the first fft256_4step call.
__device__ __forceinline__ void init_twt(float2* twt, int t) {
  int s = t >> 4, k2 = t & 15;
  float sn, cs;
  sincospif((float)(s * k2) / 128.0f, &sn, &cs);
  twt[t] = make_float2(cs, -sn);
}

// Fully-unrolled 16-point DIF FFT in registers. SIGN=+1: forward (e^{-i}),
// SIGN=-1: inverse (e^{+i}), unscaled. Natural input order; on return
// reg[j] holds X[rev4(j)].
template <int SIGN>
__device__ __forceinline__ void fft16(float* xr, float* xi) {
  const float g = (SIGN > 0) ? 1.0f : -1.0f;
  {  // stage len=16
    const float WC[8] = {1.f, C1c, RTc, S1c, 0.f, -S1c, -RTc, -C1c};
    const float WS[8] = {0.f, -S1c, -RTc, -C1c, -1.f, -C1c, -RTc, -S1c};
#pragma unroll
    for (int j = 0; j < 8; j++) {
      float ur = xr[j], ui = xi[j], vr = xr[j + 8], vi = xi[j + 8];
      float dr = ur - vr, di = ui - vi;
      xr[j] = ur + vr; xi[j] = ui + vi;
      float wc = WC[j], ws = g * WS[j];
      xr[j + 8] = dr * wc - di * ws;
      xi[j + 8] = dr * ws + di * wc;
    }
  }
  {  // stage len=8
    const float WC[4] = {1.f, RTc, 0.f, -RTc};
    const float WS[4] = {0.f, -RTc, -1.f, -RTc};
#pragma unroll
    for (int b = 0; b < 16; b += 8)
#pragma unroll
      for (int j = 0; j < 4; j++) {
        float ur = xr[b + j], ui = xi[b + j];
        float vr = xr[b + j + 4], vi = xi[b + j + 4];
        float dr = ur - vr, di = ui - vi;
        xr[b + j] = ur + vr; xi[b + j] = ui + vi;
        float wc = WC[j], ws = g * WS[j];
        xr[b + j + 4] = dr * wc - di * ws;
        xi[b + j + 4] = dr * ws + di * wc;
      }
  }
  {  // stage len=4: twiddles (1,0) and (0,-g)
#pragma unroll
    for (int b = 0; b < 16; b += 4) {
      {
        float ur = xr[b], ui = xi[b], vr = xr[b + 2], vi = xi[b + 2];
        xr[b] = ur + vr; xi[b] = ui + vi;
        xr[b + 2] = ur - vr; xi[b + 2] = ui - vi;
      }
      {
        float ur = xr[b + 1], ui = xi[b + 1], vr = xr[b + 3], vi = xi[b + 3];
        float dr = ur - vr, di = ui - vi;
        xr[b + 1] = ur + vr; xi[b + 1] = ui + vi;
        xr[b + 3] = g * di;   // (dr+i di)*(0,-g)
        xi[b + 3] = -g * dr;
      }
    }
  }
  {  // stage len=2
#pragma unroll
    for (int b = 0; b < 16; b += 2) {
      float ur = xr[b], ui = xi[b], vr = xr[b + 1], vi = xi[b + 1];
      xr[b] = ur + vr; xi[b] = ui + vi;
      xr[b + 1] = ur - vr; xi[b + 1] = ui - vi;
    }
  }
}

// Four-step 256-pt FFT: input regs v[m] = in[s + 16*m] (m=0..15) for thread
// s in [0,16). Uses re[]/im[] (>=256 floats) as transpose scratch (destroyed).
// twt is the init_twt table (reads are pre-first-internal-barrier: the CALLER
// must barrier between init_twt and this call). On return
// reg[j] = OUT[16*rev4(j) + s]. Contains 3 block-wide barriers: ALL threads
// of the block must call uniformly.
template <int SIGN>
__device__ __forceinline__ void fft256_4step(float* vr, float* vi,
                                             float* re, float* im, int s,
                                             const float2* twt) {
  fft16<SIGN>(vr, vi);
#pragma unroll
  for (int j = 1; j < 16; j++) {  // j=0 -> k2=0 -> W^0=1
    const int k2 = rev4(j);
    float2 w = twt[s * 16 + k2];
    float wc = w.x;
    float ws = (SIGN > 0) ? w.y : -w.y;
    float r = vr[j] * wc - vi[j] * ws;
    vi[j] = vr[j] * ws + vi[j] * wc;
    vr[j] = r;
  }
  __syncthreads();
#pragma unroll
  for (int j = 0; j < 16; j++) {  // write G'[s][k2] at k2*16 + (s^k2)
    const int k2 = rev4(j);
    const int p = k2 * 16 + (s ^ k2);
    re[p] = vr[j]; im[p] = vi[j];
  }
  __syncthreads();
#pragma unroll
  for (int n1 = 0; n1 < 16; n1++) {  // read G'[n1][s] at s*16 + (n1^s)
    const int p = s * 16 + (n1 ^ s);
    vr[n1] = re[p]; vi[n1] = im[p];
  }
  __syncthreads();
  fft16<SIGN>(vr, vi);
}

// K1: real row-FFT along W, TWO ROWS PACKED per complex FFT (z = a + i*b),
// 32 rows per block. Unpack Xa/Xb from Z[k], conj(Z[256-k]) during the
// transposed store to S[B*C][Wf][H]. Forward ortho 1/256 applied at load.
__global__ __launch_bounds__(256) void k_rowfft(const float* __restrict__ x,
                                                float2* __restrict__ S) {
  int blk = blockIdx.x;
  int bc = blk >> 3;            // B*C plane, 0..511
  int h0 = (blk & 7) << 5;      // first of 32 rows
  __shared__ __align__(16) float zr[16][LSTR], zi[16][LSTR];
  __shared__ __align__(16) float2 twt[256];
  int t = threadIdx.x;
  init_twt(&twt[0], t);
  const float4* xrow =
      (const float4*)(x + (size_t)bc * (Hn * Wn) + (size_t)h0 * Wn);
  const float sc = 1.0f / 256.0f;
#pragma unroll
  for (int j = 0; j < 8; j++) {
    int f4 = t + j * 256;        // 0..2047 float4s = 32 rows * 256 floats
    float4 v = xrow[f4];
    int r = f4 >> 6;             // row 0..31 (wave-uniform)
    int i = (f4 << 2) & 255;
    float* dst = (r & 1) ? &zi[r >> 1][i] : &zr[r >> 1][i];
    *(float4*)dst = make_float4(v.x * sc, v.y * sc, v.z * sc, v.w * sc);
  }
  __syncthreads();                // orders x-staging AND twt before use
  int p = t >> 4, s = t & 15;
  float vr[16], vi[16];
#pragma unroll
  for (int m = 0; m < 16; m++) {
    vr[m] = zr[p][s + 16 * m];
    vi[m] = zi[p][s + 16 * m];
  }
  fft256_4step<1>(vr, vi, &zr[p][0], &zi[p][0], s, &twt[0]);
#pragma unroll
  for (int j = 0; j < 16; j++) {   // Z back to LDS in k-order
    int h = 16 * rev4(j) + s;
    zr[p][h] = vr[j]; zi[p][h] = vi[j];
  }
  __syncthreads();
  // unpack + transposed store: row 2p: A = (Z[k]+conj(Z[nk]))/2,
  // row 2p+1: B = (Z[k]-conj(Z[nk]))/(2i);   nk = (256-k) & 255
  for (int f = t; f < WFn * 32; f += 256) {
    int wf = f >> 5, rr = f & 31;
    int pp = rr >> 1;
    int nk = (256 - wf) & 255;
    float zkr = zr[pp][wf], zki = zi[pp][wf];
    float znr = zr[pp][nk], zni = zi[pp][nk];
    float re_, im_;
    if ((rr & 1) == 0) { re_ = 0.5f * (zkr + znr); im_ = 0.5f * (zki - zni); }
    else               { re_ = 0.5f * (zki + zni); im_ = 0.5f * (znr - zkr); }
    S[((size_t)bc * WFn + wf) * Hn + (h0 + rr)] = make_float2(re_, im_);
  }
}

// K2 (fused): per (b, block k, wcol): forward 256-pt FFT along H for 16
// channels (four-step in registers), complex block-MLP (packed-fp32) +
// softshrink gate at each h, inverse FFT along H. In-place on S.
__global__ __launch_bounds__(256) void k_spectral(float2* __restrict__ S,
                                                  const float* __restrict__ w1,
                                                  const float* __restrict__ b1,
                                                  const float* __restrict__ w2,
                                                  const float* __restrict__ b2) {
  int blk = blockIdx.x;
  int wcol = blk % WFn;
  int bk = blk / WFn;
  int k = bk & 7;
  int b = bk >> 3;
  __shared__ __align__(16) float ar[16][LSTR], ai[16][LSTR];
  __shared__ __align__(16) float2 twt[256];
  __shared__ __align__(16) float w1r[256], w1i[256], w2r[256], w2i[256];
  __shared__ float b1r[16], b1i[16], b2r[16], b2i[16];
  int t = threadIdx.x;
  init_twt(&twt[0], t);
  // weights for this block k: w[part][k][i][o], i-major 16x16
  w1r[t] = w1[k * 256 + t];        w1i[t] = w1[(8 + k) * 256 + t];
  w2r[t] = w2[k * 256 + t];        w2i[t] = w2[(8 + k) * 256 + t];
  if (t < 16) {
    b1r[t] = b1[k * 16 + t];       b1i[t] = b1[(8 + k) * 16 + t];
    b2r[t] = b2[k * 16 + t];       b2i[t] = b2[(8 + k) * 16 + t];
  }
  __syncthreads();                 // twt + weights visible before first use
  int c = t >> 4, s = t & 15;
  float2* col = S + ((size_t)(b * Cn + k * BLn + c) * WFn + wcol) * Hn;
  float vr[16], vi[16];
#pragma unroll
  for (int m = 0; m < 16; m++) {   // strided load: 16 lanes x 8B contiguous
    float2 z = col[s + 16 * m];
    vr[m] = z.x; vi[m] = z.y;
  }
  fft256_4step<1>(vr, vi, &ar[c][0], &ai[c][0], s, &twt[0]);
#pragma unroll
  for (int j = 0; j < 16; j++) {   // spectrum into LDS in h-order
    int h = 16 * rev4(j) + s;
    ar[c][h] = vr[j]; ai[c][h] = vi[j];
  }
  __syncthreads();

  // ---- block MLP (float2 output-pairs -> v_pk_fma_f32) + softshrink ----
  {
    const int h = t;
    const float4* W1R = (const float4*)w1r;
    const float4* W1I = (const float4*)w1i;
    const float4* W2R = (const float4*)w2r;
    const float4* W2I = (const float4*)w2i;
    // o1p[q] = (o1r[2q], o1r[2q+1]); o1q[q] = (o1i[2q], o1i[2q+1])
    float2 o1p[8], o1q[8];
#pragma unroll
    for (int q = 0; q < 8; q++) {
      o1p[q] = make_float2(b1r[2 * q], b1r[2 * q + 1]);
      o1q[q] = make_float2(b1i[2 * q], b1i[2 * q + 1]);
    }
#pragma unroll
    for (int i = 0; i < 16; i++) {
      float xr_ = ar[i][h], xi_ = ai[i][h];
      float2 xr2 = make_float2(xr_, xr_);
      float2 xi2 = make_float2(xi_, xi_);
      float2 xn2 = make_float2(-xi_, -xi_);
#pragma unroll
      for (int oq = 0; oq < 4; oq++) {
        float4 wr = W1R[i * 4 + oq];
        float4 wi = W1I[i * 4 + oq];
        float2 wr0 = make_float2(wr.x, wr.y), wr1 = make_float2(wr.z, wr.w);
        float2 wi0 = make_float2(wi.x, wi.y), wi1 = make_float2(wi.z, wi.w);
        o1p[2 * oq + 0] = pkfma(xr2, wr0, pkfma(xn2, wi0, o1p[2 * oq + 0]));
        o1p[2 * oq + 1] = pkfma(xr2, wr1, pkfma(xn2, wi1, o1p[2 * oq + 1]));
        o1q[2 * oq + 0] = pkfma(xi2, wr0, pkfma(xr2, wi0, o1q[2 * oq + 0]));
        o1q[2 * oq + 1] = pkfma(xi2, wr1, pkfma(xr2, wi1, o1q[2 * oq + 1]));
      }
    }
#pragma unroll
    for (int q = 0; q < 8; q++) {   // ReLU (v_pk_max_f32)
      o1p[q] = make_float2(fmaxf(o1p[q].x, 0.f), fmaxf(o1p[q].y, 0.f));
      o1q[q] = make_float2(fmaxf(o1q[q].x, 0.f), fmaxf(o1q[q].y, 0.f));
    }
    float2 o2p[8], o2q[8];
#pragma unroll
    for (int q = 0; q < 8; q++) {
      o2p[q] = make_float2(b2r[2 * q], b2r[2 * q + 1]);
      o2q[q] = make_float2(b2i[2 * q], b2i[2 * q + 1]);
    }
#pragma unroll
    for (int i = 0; i < 16; i++) {
      float pr = (i & 1) ? o1p[i >> 1].y : o1p[i >> 1].x;
      float pi_ = (i & 1) ? o1q[i >> 1].y : o1q[i >> 1].x;
      float2 pr2 = make_float2(pr, pr);
      float2 pi2 = make_float2(pi_, pi_);
      float2 pn2 = make_float2(-pi_, -pi_);
#pragma unroll
      for (int oq = 0; oq < 4; oq++) {
        float4 wr = W2R[i * 4 + oq];
        float4 wi = W2I[i * 4 + oq];
        float2 wr0 = make_float2(wr.x, wr.y), wr1 = make_float2(wr.z, wr.w);
        float2 wi0 = make_float2(wi.x, wi.y), wi1 = make_float2(wi.z, wi.w);
        o2p[2 * oq + 0] = pkfma(pr2, wr0, pkfma(pn2, wi0, o2p[2 * oq + 0]));
        o2p[2 * oq + 1] = pkfma(pr2, wr1, pkfma(pn2, wi1, o2p[2 * oq + 1]));
        o2q[2 * oq + 0] = pkfma(pi2, wr0, pkfma(pr2, wi0, o2q[2 * oq + 0]));
        o2q[2 * oq + 1] = pkfma(pi2, wr1, pkfma(pr2, wi1, o2q[2 * oq + 1]));
      }
    }
#pragma unroll
    for (int o = 0; o < 16; o++) {
      float vr_ = (o & 1) ? o2p[o >> 1].y : o2p[o >> 1].x;
      float vi_ = (o & 1) ? o2q[o >> 1].y : o2q[o >> 1].x;
      float sr = copysignf(fmaxf(fabsf(vr_) - LAMv, 0.0f), vr_);
      float si = copysignf(fmaxf(fabsf(vi_) - LAMv, 0.0f), vi_);
      float fr = ar[o][h], fi = ai[o][h];  // xf (2D spectrum) in LDS
      ar[o][h] = sr * fr - si * fi;
      ai[o][h] = sr * fi + si * fr;
    }
  }
  __syncthreads();
#pragma unroll
  for (int m = 0; m < 16; m++) {
    vr[m] = ar[c][s + 16 * m];
    vi[m] = ai[c][s + 16 * m];
  }
  fft256_4step<-1>(vr, vi, &ar[c][0], &ai[c][0], s, &twt[0]);
#pragma unroll
  for (int j = 0; j < 16; j++) {
    int h = 16 * rev4(j) + s;
    col[h] = make_float2(vr[j], vi[j]);
  }
}

// K3: inverse row FFT along W, TWO ROWS PACKED per complex FFT:
// Z[k] = A[k] + i*B[k]  =>  ifft(Z) = a + i*b (both real rows at once).
// Hermitian extension folded into the pack. 32 rows per block.
// + ortho 1/256 + residual add.
__global__ __launch_bounds__(256) void k_invrow(const float2* __restrict__ S,
                                                const float* __restrict__ x,
                                                float* __restrict__ out) {
  int blk = blockIdx.x;
  int bc = blk >> 3;            // 0..511
  int h0 = (blk & 7) << 5;      // first of 32 rows
  __shared__ __align__(16) float zr[16][LSTR], zi[16][LSTR];
  __shared__ __align__(16) float2 twt[256];
  int t = threadIdx.x;
  init_twt(&twt[0], t);
  // pack: v = (Ar,Ai,Br,Bi) from adjacent h-pair (one float4).
  // Z[p][wf]     = (Ar - Bi,  Ai + Br)
  // Z[p][256-wf] = (Ar + Bi,  Br - Ai)   for wf in 1..127
  const float4* S4 = (const float4*)S;
  for (int f = t; f < WFn * 16; f += 256) {
    int wf = f >> 4, p = f & 15;
    float4 v = S4[((size_t)bc * WFn + wf) * (Hn / 2) + (h0 >> 1) + p];
    zr[p][wf] = v.x - v.w;
    zi[p][wf] = v.y + v.z;
    if (wf >= 1 && wf <= 127) {
      zr[p][256 - wf] = v.x + v.w;
      zi[p][256 - wf] = v.z - v.y;
    }
  }
  __syncthreads();                // orders pack AND twt before use
  int p = t >> 4, s = t & 15;
  float vr[16], vi[16];
#pragma unroll
  for (int m = 0; m < 16; m++) {
    vr[m] = zr[p][s + 16 * m];
    vi[m] = zi[p][s + 16 * m];
  }
  fft256_4step<-1>(vr, vi, &zr[p][0], &zi[p][0], s, &twt[0]);
#pragma unroll
  for (int j = 0; j < 16; j++) {  // z back in natural w-order (re AND im)
    int w = 16 * rev4(j) + s;
    zr[p][w] = vr[j]; zi[p][w] = vi[j];
  }
  __syncthreads();
  const float sc = 1.0f / 256.0f;  // inverse ortho factor for both axes
  size_t base = (size_t)bc * (Hn * Wn) + (size_t)h0 * Wn;
  const float4* x4 = (const float4*)(x + base);
  float4* o4 = (float4*)(out + base);
#pragma unroll
  for (int j = 0; j < 8; j++) {
    int f4 = t + j * 256;          // 0..2047
    int rr = f4 >> 6;              // row 0..31 (wave-uniform)
    int i = (f4 << 2) & 255;
    const float* src = (rr & 1) ? &zi[rr >> 1][i] : &zr[rr >> 1][i];
    float4 v = *(const float4*)src;
    float4 xv = x4[f4];
    o4[f4] = make_float4(fmaf(v.x, sc, xv.x), fmaf(v.y, sc, xv.y),
                         fmaf(v.z, sc, xv.z), fmaf(v.w, sc, xv.w));
  }
}

extern "C" void kernel_launch(void* const* d_in, const int* in_sizes, int n_in,
                              void* d_out, int out_size, void* d_ws,
                              size_t ws_size, hipStream_t stream) {
  const float* x  = (const float*)d_in[0];
  const float* w1 = (const float*)d_in[1];
  const float* b1 = (const float*)d_in[2];
  const float* w2 = (const float*)d_in[3];
  const float* b2 = (const float*)d_in[4];
  float* out = (float*)d_out;
  float2* S = (float2*)d_ws;  // [B*C][Wf][H] complex, ~135 MB

  k_rowfft<<<Bn * Cn * (Hn / 32), 256, 0, stream>>>(x, S);
  k_spectral<<<Bn * NBn * WFn, 256, 0, stream>>>(S, w1, b1, w2, b2);
  k_invrow<<<Bn * Cn * (Hn / 32), 256, 0, stream>>>(S, x, out);
}

// Round 7
// 421.714 us; speedup vs baseline: 1.0872x; 1.0872x over previous
//
#include <hip/hip_runtime.h>
#include <math.h>

#define Bn 4
#define Cn 128
#define Hn 256
#define Wn 256
#define WFn 129
#define NBn 8
#define BLn 16
#define LAMv 0.01f
// LDS row stride (floats). 272 = 16 mod 32 banks: the 4 c-groups of a wave
// land on complementary bank halves -> exact 2-way aliasing (free) for the
// four-step transpose, h-order stores, and MLP reads. Also 16B-aligned.
#define LSTR 272

#define C1c 0.9238795325112867f  // cos(pi/8)
#define S1c 0.3826834323650898f  // sin(pi/8)
#define RTc 0.7071067811865476f  // sqrt(2)/2

__device__ constexpr int rev4(int j) {
  return ((j & 1) << 3) | ((j & 2) << 1) | ((j & 4) >> 1) | ((j & 8) >> 3);
}

// elementwise float2 fma: SLP-vectorizes to v_pk_fma_f32 on gfx950
__device__ __forceinline__ float2 pkfma(float2 a, float2 b, float2 c) {
  return make_float2(fmaf(a.x, b.x, c.x), fmaf(a.y, b.y, c.y));
}

// Twiddle table, layout twt[k2*16 + s] = e^{-i*pi*s*k2/128} = (cos, -sin).
// Layout note: reads use fixed k2, varying s -> byte = (k2*16+s)*8, bank =
// 2s mod 32: the 16 distinct lane addresses cover all 32 banks exactly once
// (conflict-free). [The s-major layout was a 16-way conflict: bank = 2*k2,
// fixed across lanes -- measured 2.8e7 conflicts/dispatch in round 6.]
// Caller must __syncthreads() between init_twt and the first fft256_4step.
__device__ __forceinline__ void init_twt(float2* twt, int t) {
  int k2 = t >> 4, s = t & 15;
  float sn, cs;
  sincospif((float)(s * k2) / 128.0f, &sn, &cs);
  twt[t] = make_float2(cs, -sn);
}

// Fully-unrolled 16-point DIF FFT in registers. SIGN=+1: forward (e^{-i}),
// SIGN=-1: inverse (e^{+i}), unscaled. Natural input order; on return
// reg[j] holds X[rev4(j)].
template <int SIGN>
__device__ __forceinline__ void fft16(float* xr, float* xi) {
  const float g = (SIGN > 0) ? 1.0f : -1.0f;
  {  // stage len=16
    const float WC[8] = {1.f, C1c, RTc, S1c, 0.f, -S1c, -RTc, -C1c};
    const float WS[8] = {0.f, -S1c, -RTc, -C1c, -1.f, -C1c, -RTc, -S1c};
#pragma unroll
    for (int j = 0; j < 8; j++) {
      float ur = xr[j], ui = xi[j], vr = xr[j + 8], vi = xi[j + 8];
      float dr = ur - vr, di = ui - vi;
      xr[j] = ur + vr; xi[j] = ui + vi;
      float wc = WC[j], ws = g * WS[j];
      xr[j + 8] = dr * wc - di * ws;
      xi[j + 8] = dr * ws + di * wc;
    }
  }
  {  // stage len=8
    const float WC[4] = {1.f, RTc, 0.f, -RTc};
    const float WS[4] = {0.f, -RTc, -1.f, -RTc};
#pragma unroll
    for (int b = 0; b < 16; b += 8)
#pragma unroll
      for (int j = 0; j < 4; j++) {
        float ur = xr[b + j], ui = xi[b + j];
        float vr = xr[b + j + 4], vi = xi[b + j + 4];
        float dr = ur - vr, di = ui - vi;
        xr[b + j] = ur + vr; xi[b + j] = ui + vi;
        float wc = WC[j], ws = g * WS[j];
        xr[b + j + 4] = dr * wc - di * ws;
        xi[b + j + 4] = dr * ws + di * wc;
      }
  }
  {  // stage len=4: twiddles (1,0) and (0,-g)
#pragma unroll
    for (int b = 0; b < 16; b += 4) {
      {
        float ur = xr[b], ui = xi[b], vr = xr[b + 2], vi = xi[b + 2];
        xr[b] = ur + vr; xi[b] = ui + vi;
        xr[b + 2] = ur - vr; xi[b + 2] = ui - vi;
      }
      {
        float ur = xr[b + 1], ui = xi[b + 1], vr = xr[b + 3], vi = xi[b + 3];
        float dr = ur - vr, di = ui - vi;
        xr[b + 1] = ur + vr; xi[b + 1] = ui + vi;
        xr[b + 3] = g * di;   // (dr+i di)*(0,-g)
        xi[b + 3] = -g * dr;
      }
    }
  }
  {  // stage len=2
#pragma unroll
    for (int b = 0; b < 16; b += 2) {
      float ur = xr[b], ui = xi[b], vr = xr[b + 1], vi = xi[b + 1];
      xr[b] = ur + vr; xi[b] = ui + vi;
      xr[b + 1] = ur - vr; xi[b + 1] = ui - vi;
    }
  }
}

// Four-step 256-pt FFT: input regs v[m] = in[s + 16*m] (m=0..15) for thread
// s in [0,16). Uses re[]/im[] (>=256 floats) as transpose scratch (destroyed).
// twt is the init_twt table. On return reg[j] = OUT[16*rev4(j) + s].
// Contains 3 block-wide barriers: ALL threads must call uniformly. The first
// barrier orders prior reads of re/im before the scratch writes.
template <int SIGN>
__device__ __forceinline__ void fft256_4step(float* vr, float* vi,
                                             float* re, float* im, int s,
                                             const float2* twt) {
  fft16<SIGN>(vr, vi);
#pragma unroll
  for (int j = 1; j < 16; j++) {  // j=0 -> k2=0 -> W^0=1
    const int k2 = rev4(j);
    float2 w = twt[k2 * 16 + s];
    float wc = w.x;
    float ws = (SIGN > 0) ? w.y : -w.y;
    float r = vr[j] * wc - vi[j] * ws;
    vi[j] = vr[j] * ws + vi[j] * wc;
    vr[j] = r;
  }
  __syncthreads();
#pragma unroll
  for (int j = 0; j < 16; j++) {  // write G'[s][k2] at k2*16 + (s^k2)
    const int k2 = rev4(j);
    const int p = k2 * 16 + (s ^ k2);
    re[p] = vr[j]; im[p] = vi[j];
  }
  __syncthreads();
#pragma unroll
  for (int n1 = 0; n1 < 16; n1++) {  // read G'[n1][s] at s*16 + (n1^s)
    const int p = s * 16 + (n1 ^ s);
    vr[n1] = re[p]; vi[n1] = im[p];
  }
  __syncthreads();
  fft16<SIGN>(vr, vi);
}

// K1: real row-FFT along W, TWO ROWS PACKED per complex FFT (z = a + i*b),
// 32 rows per block. Unpack Xa/Xb from Z[k], conj(Z[256-k]) during the
// transposed store to S[B*C][Wf][H]. Forward ortho 1/256 applied at load.
__global__ __launch_bounds__(256) void k_rowfft(const float* __restrict__ x,
                                                float2* __restrict__ S) {
  int blk = blockIdx.x;
  int bc = blk >> 3;            // B*C plane, 0..511
  int h0 = (blk & 7) << 5;      // first of 32 rows
  __shared__ __align__(16) float zr[16][LSTR], zi[16][LSTR];
  __shared__ __align__(16) float2 twt[256];
  int t = threadIdx.x;
  init_twt(&twt[0], t);
  const float4* xrow =
      (const float4*)(x + (size_t)bc * (Hn * Wn) + (size_t)h0 * Wn);
  const float sc = 1.0f / 256.0f;
#pragma unroll
  for (int j = 0; j < 8; j++) {
    int f4 = t + j * 256;        // 0..2047 float4s = 32 rows * 256 floats
    float4 v = xrow[f4];
    int r = f4 >> 6;             // row 0..31 (wave-uniform)
    int i = (f4 << 2) & 255;
    float* dst = (r & 1) ? &zi[r >> 1][i] : &zr[r >> 1][i];
    *(float4*)dst = make_float4(v.x * sc, v.y * sc, v.z * sc, v.w * sc);
  }
  __syncthreads();                // orders x-staging AND twt before use
  int p = t >> 4, s = t & 15;
  float vr[16], vi[16];
#pragma unroll
  for (int m = 0; m < 16; m++) {
    vr[m] = zr[p][s + 16 * m];
    vi[m] = zi[p][s + 16 * m];
  }
  fft256_4step<1>(vr, vi, &zr[p][0], &zi[p][0], s, &twt[0]);
#pragma unroll
  for (int j = 0; j < 16; j++) {   // Z back to LDS in k-order
    int h = 16 * rev4(j) + s;
    zr[p][h] = vr[j]; zi[p][h] = vi[j];
  }
  __syncthreads();
  // unpack + transposed store: row 2p: A = (Z[k]+conj(Z[nk]))/2,
  // row 2p+1: B = (Z[k]-conj(Z[nk]))/(2i);   nk = (256-k) & 255
  for (int f = t; f < WFn * 32; f += 256) {
    int wf = f >> 5, rr = f & 31;
    int pp = rr >> 1;
    int nk = (256 - wf) & 255;
    float zkr = zr[pp][wf], zki = zi[pp][wf];
    float znr = zr[pp][nk], zni = zi[pp][nk];
    float re_, im_;
    if ((rr & 1) == 0) { re_ = 0.5f * (zkr + znr); im_ = 0.5f * (zki - zni); }
    else               { re_ = 0.5f * (zki + zni); im_ = 0.5f * (znr - zkr); }
    S[((size_t)bc * WFn + wf) * Hn + (h0 + rr)] = make_float2(re_, im_);
  }
}

// K2 (fused): per (b, block k, wf-PAIR): forward 256-pt FFT along H for 16
// channels x 2 columns, complex block-MLP (packed-fp32, weights amortized
// over both columns) + softshrink gate, inverse FFT along H. In-place on S.
// 2 columns/block halves the per-h broadcast weight ds_read_b128 cost.
__global__ __launch_bounds__(256) void k_spectral(float2* __restrict__ S,
                                                  const float* __restrict__ w1,
                                                  const float* __restrict__ b1,
                                                  const float* __restrict__ w2,
                                                  const float* __restrict__ b2) {
  int blk = blockIdx.x;
  int wi = blk % 65;             // column pair index
  int bk = blk / 65;
  int k = bk & 7;
  int b = bk >> 3;
  int wcol0 = wi * 2;
  const bool has1 = (wcol0 + 1) < WFn;   // wi=64 -> lone column 128
  __shared__ __align__(16) float ar[2][16][LSTR], ai[2][16][LSTR];
  __shared__ __align__(16) float2 twt[256];
  __shared__ __align__(16) float w1r[256], w1i[256], w2r[256], w2i[256];
  __shared__ float b1r[16], b1i[16], b2r[16], b2i[16];
  int t = threadIdx.x;
  init_twt(&twt[0], t);
  // weights for this block k: w[part][k][i][o], i-major 16x16
  w1r[t] = w1[k * 256 + t];        w1i[t] = w1[(8 + k) * 256 + t];
  w2r[t] = w2[k * 256 + t];        w2i[t] = w2[(8 + k) * 256 + t];
  if (t < 16) {
    b1r[t] = b1[k * 16 + t];       b1i[t] = b1[(8 + k) * 16 + t];
    b2r[t] = b2[k * 16 + t];       b2i[t] = b2[(8 + k) * 16 + t];
  }
  __syncthreads();                 // twt + weights visible before first use
  int c = t >> 4, s = t & 15;
  float2* col0 = S + ((size_t)(b * Cn + k * BLn + c) * WFn + wcol0) * Hn;
  float2* col1 = col0 + Hn;        // next wf, same channel
  float vr[16], vi[16];
  // ---- forward FFT, column 0 ----
#pragma unroll
  for (int m = 0; m < 16; m++) {
    float2 z = col0[s + 16 * m];
    vr[m] = z.x; vi[m] = z.y;
  }
  fft256_4step<1>(vr, vi, &ar[0][c][0], &ai[0][c][0], s, &twt[0]);
#pragma unroll
  for (int j = 0; j < 16; j++) {
    int h = 16 * rev4(j) + s;
    ar[0][c][h] = vr[j]; ai[0][c][h] = vi[j];
  }
  // ---- forward FFT, column 1 (uniform barriers; data predicated) ----
  if (has1) {
#pragma unroll
    for (int m = 0; m < 16; m++) {
      float2 z = col1[s + 16 * m];
      vr[m] = z.x; vi[m] = z.y;
    }
  }
  fft256_4step<1>(vr, vi, &ar[1][c][0], &ai[1][c][0], s, &twt[0]);
#pragma unroll
  for (int j = 0; j < 16; j++) {
    int h = 16 * rev4(j) + s;
    ar[1][c][h] = vr[j]; ai[1][c][h] = vi[j];
  }
  __syncthreads();

  // ---- dual-column block MLP (v_pk_fma_f32 pairs) + softshrink gate ----
  {
    const int h = t;
    const float4* W1R = (const float4*)w1r;
    const float4* W1I = (const float4*)w1i;
    const float4* W2R = (const float4*)w2r;
    const float4* W2I = (const float4*)w2i;
    float2 o1p[2][8], o1q[2][8];
#pragma unroll
    for (int q = 0; q < 8; q++) {
      float2 bp = make_float2(b1r[2 * q], b1r[2 * q + 1]);
      float2 bq = make_float2(b1i[2 * q], b1i[2 * q + 1]);
      o1p[0][q] = bp; o1p[1][q] = bp;
      o1q[0][q] = bq; o1q[1][q] = bq;
    }
#pragma unroll
    for (int i = 0; i < 16; i++) {
      float xr0 = ar[0][i][h], xi0 = ai[0][i][h];
      float xr1 = ar[1][i][h], xi1 = ai[1][i][h];
      float2 xr20 = make_float2(xr0, xr0), xi20 = make_float2(xi0, xi0);
      float2 xn20 = make_float2(-xi0, -xi0);
      float2 xr21 = make_float2(xr1, xr1), xi21 = make_float2(xi1, xi1);
      float2 xn21 = make_float2(-xi1, -xi1);
#pragma unroll
      for (int oq = 0; oq < 4; oq++) {
        float4 wr = W1R[i * 4 + oq];
        float4 wi = W1I[i * 4 + oq];
        float2 wr0 = make_float2(wr.x, wr.y), wr1 = make_float2(wr.z, wr.w);
        float2 wi0 = make_float2(wi.x, wi.y), wi1 = make_float2(wi.z, wi.w);
        o1p[0][2*oq+0] = pkfma(xr20, wr0, pkfma(xn20, wi0, o1p[0][2*oq+0]));
        o1p[0][2*oq+1] = pkfma(xr20, wr1, pkfma(xn20, wi1, o1p[0][2*oq+1]));
        o1q[0][2*oq+0] = pkfma(xi20, wr0, pkfma(xr20, wi0, o1q[0][2*oq+0]));
        o1q[0][2*oq+1] = pkfma(xi20, wr1, pkfma(xr20, wi1, o1q[0][2*oq+1]));
        o1p[1][2*oq+0] = pkfma(xr21, wr0, pkfma(xn21, wi0, o1p[1][2*oq+0]));
        o1p[1][2*oq+1] = pkfma(xr21, wr1, pkfma(xn21, wi1, o1p[1][2*oq+1]));
        o1q[1][2*oq+0] = pkfma(xi21, wr0, pkfma(xr21, wi0, o1q[1][2*oq+0]));
        o1q[1][2*oq+1] = pkfma(xi21, wr1, pkfma(xr21, wi1, o1q[1][2*oq+1]));
      }
    }
#pragma unroll
    for (int u = 0; u < 2; u++)
#pragma unroll
      for (int q = 0; q < 8; q++) {   // ReLU
        o1p[u][q] = make_float2(fmaxf(o1p[u][q].x, 0.f), fmaxf(o1p[u][q].y, 0.f));
        o1q[u][q] = make_float2(fmaxf(o1q[u][q].x, 0.f), fmaxf(o1q[u][q].y, 0.f));
      }
    float2 o2p[2][8], o2q[2][8];
#pragma unroll
    for (int q = 0; q < 8; q++) {
      float2 bp = make_float2(b2r[2 * q], b2r[2 * q + 1]);
      float2 bq = make_float2(b2i[2 * q], b2i[2 * q + 1]);
      o2p[0][q] = bp; o2p[1][q] = bp;
      o2q[0][q] = bq; o2q[1][q] = bq;
    }
#pragma unroll
    for (int i = 0; i < 16; i++) {
      float pr0 = (i & 1) ? o1p[0][i >> 1].y : o1p[0][i >> 1].x;
      float pi0 = (i & 1) ? o1q[0][i >> 1].y : o1q[0][i >> 1].x;
      float pr1 = (i & 1) ? o1p[1][i >> 1].y : o1p[1][i >> 1].x;
      float pi1 = (i & 1) ? o1q[1][i >> 1].y : o1q[1][i >> 1].x;
      float2 pr20 = make_float2(pr0, pr0), pi20 = make_float2(pi0, pi0);
      float2 pn20 = make_float2(-pi0, -pi0);
      float2 pr21 = make_float2(pr1, pr1), pi21 = make_float2(pi1, pi1);
      float2 pn21 = make_float2(-pi1, -pi1);
#pragma unroll
      for (int oq = 0; oq < 4; oq++) {
        float4 wr = W2R[i * 4 + oq];
        float4 wi = W2I[i * 4 + oq];
        float2 wr0 = make_float2(wr.x, wr.y), wr1 = make_float2(wr.z, wr.w);
        float2 wi0 = make_float2(wi.x, wi.y), wi1 = make_float2(wi.z, wi.w);
        o2p[0][2*oq+0] = pkfma(pr20, wr0, pkfma(pn20, wi0, o2p[0][2*oq+0]));
        o2p[0][2*oq+1] = pkfma(pr20, wr1, pkfma(pn20, wi1, o2p[0][2*oq+1]));
        o2q[0][2*oq+0] = pkfma(pi20, wr0, pkfma(pr20, wi0, o2q[0][2*oq+0]));
        o2q[0][2*oq+1] = pkfma(pi20, wr1, pkfma(pr20, wi1, o2q[0][2*oq+1]));
        o2p[1][2*oq+0] = pkfma(pr21, wr0, pkfma(pn21, wi0, o2p[1][2*oq+0]));
        o2p[1][2*oq+1] = pkfma(pr21, wr1, pkfma(pn21, wi1, o2p[1][2*oq+1]));
        o2q[1][2*oq+0] = pkfma(pi21, wr0, pkfma(pr21, wi0, o2q[1][2*oq+0]));
        o2q[1][2*oq+1] = pkfma(pi21, wr1, pkfma(pr21, wi1, o2q[1][2*oq+1]));
      }
    }
#pragma unroll
    for (int u = 0; u < 2; u++)
#pragma unroll
      for (int o = 0; o < 16; o++) {
        float vr_ = (o & 1) ? o2p[u][o >> 1].y : o2p[u][o >> 1].x;
        float vi_ = (o & 1) ? o2q[u][o >> 1].y : o2q[u][o >> 1].x;
        float sr = copysignf(fmaxf(fabsf(vr_) - LAMv, 0.0f), vr_);
        float si = copysignf(fmaxf(fabsf(vi_) - LAMv, 0.0f), vi_);
        float fr = ar[u][o][h], fi = ai[u][o][h];  // xf spectrum in LDS
        ar[u][o][h] = sr * fr - si * fi;
        ai[u][o][h] = sr * fi + si * fr;
      }
  }
  __syncthreads();
  // ---- inverse FFT, column 0 ----
#pragma unroll
  for (int m = 0; m < 16; m++) {
    vr[m] = ar[0][c][s + 16 * m];
    vi[m] = ai[0][c][s + 16 * m];
  }
  fft256_4step<-1>(vr, vi, &ar[0][c][0], &ai[0][c][0], s, &twt[0]);
#pragma unroll
  for (int j = 0; j < 16; j++) {
    int h = 16 * rev4(j) + s;
    col0[h] = make_float2(vr[j], vi[j]);
  }
  // ---- inverse FFT, column 1 ----
#pragma unroll
  for (int m = 0; m < 16; m++) {
    vr[m] = ar[1][c][s + 16 * m];
    vi[m] = ai[1][c][s + 16 * m];
  }
  fft256_4step<-1>(vr, vi, &ar[1][c][0], &ai[1][c][0], s, &twt[0]);
  if (has1) {
#pragma unroll
    for (int j = 0; j < 16; j++) {
      int h = 16 * rev4(j) + s;
      col1[h] = make_float2(vr[j], vi[j]);
    }
  }
}

// K3: inverse row FFT along W, TWO ROWS PACKED per complex FFT:
// Z[k] = A[k] + i*B[k]  =>  ifft(Z) = a + i*b (both real rows at once).
// Hermitian extension folded into the pack. 32 rows per block.
// + ortho 1/256 + residual add.
__global__ __launch_bounds__(256) void k_invrow(const float2* __restrict__ S,
                                                const float* __restrict__ x,
                                                float* __restrict__ out) {
  int blk = blockIdx.x;
  int bc = blk >> 3;            // 0..511
  int h0 = (blk & 7) << 5;      // first of 32 rows
  __shared__ __align__(16) float zr[16][LSTR], zi[16][LSTR];
  __shared__ __align__(16) float2 twt[256];
  int t = threadIdx.x;
  init_twt(&twt[0], t);
  // pack: v = (Ar,Ai,Br,Bi) from adjacent h-pair (one float4).
  // Z[p][wf]     = (Ar - Bi,  Ai + Br)
  // Z[p][256-wf] = (Ar + Bi,  Br - Ai)   for wf in 1..127
  const float4* S4 = (const float4*)S;
  for (int f = t; f < WFn * 16; f += 256) {
    int wf = f >> 4, p = f & 15;
    float4 v = S4[((size_t)bc * WFn + wf) * (Hn / 2) + (h0 >> 1) + p];
    zr[p][wf] = v.x - v.w;
    zi[p][wf] = v.y + v.z;
    if (wf >= 1 && wf <= 127) {
      zr[p][256 - wf] = v.x + v.w;
      zi[p][256 - wf] = v.z - v.y;
    }
  }
  __syncthreads();                // orders pack AND twt before use
  int p = t >> 4, s = t & 15;
  float vr[16], vi[16];
#pragma unroll
  for (int m = 0; m < 16; m++) {
    vr[m] = zr[p][s + 16 * m];
    vi[m] = zi[p][s + 16 * m];
  }
  fft256_4step<-1>(vr, vi, &zr[p][0], &zi[p][0], s, &twt[0]);
#pragma unroll
  for (int j = 0; j < 16; j++) {  // z back in natural w-order (re AND im)
    int w = 16 * rev4(j) + s;
    zr[p][w] = vr[j]; zi[p][w] = vi[j];
  }
  __syncthreads();
  const float sc = 1.0f / 256.0f;  // inverse ortho factor for both axes
  size_t base = (size_t)bc * (Hn * Wn) + (size_t)h0 * Wn;
  const float4* x4 = (const float4*)(x + base);
  float4* o4 = (float4*)(out + base);
#pragma unroll
  for (int j = 0; j < 8; j++) {
    int f4 = t + j * 256;          // 0..2047
    int rr = f4 >> 6;              // row 0..31 (wave-uniform)
    int i = (f4 << 2) & 255;
    const float* src = (rr & 1) ? &zi[rr >> 1][i] : &zr[rr >> 1][i];
    float4 v = *(const float4*)src;
    float4 xv = x4[f4];
    o4[f4] = make_float4(fmaf(v.x, sc, xv.x), fmaf(v.y, sc, xv.y),
                         fmaf(v.z, sc, xv.z), fmaf(v.w, sc, xv.w));
  }
}

extern "C" void kernel_launch(void* const* d_in, const int* in_sizes, int n_in,
                              void* d_out, int out_size, void* d_ws,
                              size_t ws_size, hipStream_t stream) {
  const float* x  = (const float*)d_in[0];
  const float* w1 = (const float*)d_in[1];
  const float* b1 = (const float*)d_in[2];
  const float* w2 = (const float*)d_in[3];
  const float* b2 = (const float*)d_in[4];
  float* out = (float*)d_out;
  float2* S = (float2*)d_ws;  // [B*C][Wf][H] complex, ~135 MB

  k_rowfft<<<Bn * Cn * (Hn / 32), 256, 0, stream>>>(x, S);
  k_spectral<<<Bn * NBn * 65, 256, 0, stream>>>(S, w1, b1, w2, b2);
  k_invrow<<<Bn * Cn * (Hn / 32), 256, 0, stream>>>(S, x, out);
}